// Round 1
// baseline (90.704 us; speedup 1.0000x reference)
//
#include <hip/hip_runtime.h>

#define WINDOW 10
#define NT 8          // t-outputs per thread
#define NH 32         // hidden channels

__global__ __launch_bounds__(256) void hurst_kernel(
    const float* __restrict__ ret, const float* __restrict__ W1,
    const float* __restrict__ b1,  const float* __restrict__ W2,
    const float* __restrict__ b2,  float* __restrict__ out,
    int B, int T) {
  const int TV = T - WINDOW;                 // 4086 valid t's
  const int b  = blockIdx.y;
  const int t0 = (blockIdx.x * blockDim.x + threadIdx.x) * NT;
  if (t0 >= TV) return;

  const float* row = ret + (size_t)b * T;

  // Sliding window held in registers: rv[i] = returns[b, t0+i], clamped at row end
  float rv[NT + WINDOW - 1];
  #pragma unroll
  for (int i = 0; i < NT + WINDOW - 1; ++i) {
    int idx = t0 + i;
    if (idx > T - 1) idx = T - 1;            // only last thread's tail hits this
    rv[i] = row[idx];
  }

  float acc[NT];
  #pragma unroll
  for (int t = 0; t < NT; ++t) acc[t] = 0.f;

  // Layer 1 (10-tap FIR, 32 channels) fused with layer-2 accumulation.
  // W1/b1/W2 addresses are wave-uniform -> scalar loads (constant cache).
  #pragma unroll 4
  for (int h = 0; h < NH; ++h) {
    float w1h[WINDOW];
    #pragma unroll
    for (int w = 0; w < WINDOW; ++w) w1h[w] = W1[h * WINDOW + w];
    const float bb  = b1[h];
    const float w2h = W2[h];
    #pragma unroll
    for (int t = 0; t < NT; ++t) {
      float s = bb;
      #pragma unroll
      for (int w = 0; w < WINDOW; ++w) s = fmaf(rv[t + w], w1h[w], s);
      s = fmaxf(s, 0.f);                     // ReLU
      acc[t] = fmaf(s, w2h, acc[t]);         // layer-2 dot
    }
  }

  const float bb2 = b2[0];
  float* orow = out + (size_t)b * T;
  #pragma unroll
  for (int t = 0; t < NT; ++t) {
    const int tt = t0 + t;
    if (tt < TV) {
      const float z = acc[t] + bb2;
      const float y = 0.5f / (1.f + __expf(-z));
      orow[WINDOW + tt] = y;                 // out[:, 10:] = h
      if (tt == 0) {                         // out[:, 0:10] = h[:, 0] broadcast
        #pragma unroll
        for (int j = 0; j < WINDOW; ++j) orow[j] = y;
      }
    }
  }
}

extern "C" void kernel_launch(void* const* d_in, const int* in_sizes, int n_in,
                              void* d_out, int out_size, void* d_ws, size_t ws_size,
                              hipStream_t stream) {
  const float* ret = (const float*)d_in[0];
  const float* W1  = (const float*)d_in[1];
  const float* b1  = (const float*)d_in[2];
  const float* W2  = (const float*)d_in[3];
  const float* b2  = (const float*)d_in[4];
  float* out = (float*)d_out;

  const int T = 4096;
  const int B = in_sizes[0] / T;             // 2048
  const int TV = T - WINDOW;                 // 4086
  const int threads_per_row = (TV + NT - 1) / NT;   // 511

  dim3 block(256);
  dim3 grid((threads_per_row + block.x - 1) / block.x, B);
  hipLaunchKernelGGL(hurst_kernel, grid, block, 0, stream,
                     ret, W1, b1, W2, b2, out, B, T);
}

// Round 2
// 56.598 us; speedup vs baseline: 1.6026x; 1.6026x over previous
//
#include <hip/hip_runtime.h>

#define WINDOW 10
#define TDIM 4096
#define TVALID (TDIM - WINDOW)   // 4086 valid outputs per row

// bf16 fragments as i16 bits (guide: gfx950-verified fragment typing)
typedef __attribute__((ext_vector_type(8))) short bf16x8;
typedef __attribute__((ext_vector_type(16))) float f32x16;

static __device__ __forceinline__ short f2bf(float f) {
  // clang __bf16 fptrunc -> v_cvt (RNE) on gfx950
  return (short)__builtin_bit_cast(unsigned short, (__bf16)f);
}

__global__ __launch_bounds__(256) void hurst_mfma(
    const float* __restrict__ ret, const float* __restrict__ W1,
    const float* __restrict__ b1,  const float* __restrict__ W2,
    const float* __restrict__ b2,  float* __restrict__ out) {
  const int lid = threadIdx.x & 63;
  const int wv  = threadIdx.x >> 6;   // wave in block = t-segment
  const int n   = lid & 31;           // A: channel row | B: t-offset | D: t col
  const int g   = lid >> 5;           // k-group (taps 0-7 | taps 8-15)
  const bool g1 = (g == 1);

  // ---- A fragment: W1 rows, with b1 fused into tap-slot 10 (loop-invariant) ----
  bf16x8 af;
  if (!g1) {
    #pragma unroll
    for (int j = 0; j < 8; ++j) af[j] = f2bf(W1[n * WINDOW + j]);
  } else {
    af[0] = f2bf(W1[n * WINDOW + 8]);
    af[1] = f2bf(W1[n * WINDOW + 9]);
    af[2] = f2bf(b1[n]);              // k-slot 10: bias (B supplies 1.0 there)
    #pragma unroll
    for (int j = 3; j < 8; ++j) af[j] = 0;
  }

  // ---- layer-2 weight per accumulator reg: D row m = (r&3)+8*(r>>2)+4*g ----
  float w2v[16];
  #pragma unroll
  for (int r = 0; r < 16; ++r)
    w2v[r] = W2[(r & 3) + 8 * (r >> 2) + 4 * g];
  const float b2c = b2[0];

  const int row = blockIdx.x;          // one block per batch row; 4 waves = 4 segments
  const float* __restrict__ rowp = ret + (size_t)row * TDIM;
  float* __restrict__ orow = out + (size_t)row * TDIM;

  #pragma unroll 1
  for (int i = 0; i < 32; ++i) {
    const int t0   = wv * 1024 + i * 32;       // tile base, 0..4064
    const int base = t0 + n + 8 * g;

    float f[8];
    if (t0 <= 4032) {                          // fast path: all reads in-row
      #pragma unroll
      for (int j = 0; j < 8; ++j) f[j] = rowp[base + j];
    } else {                                   // tail tile t0==4064: clamp indices
      #pragma unroll
      for (int j = 0; j < 8; ++j) {
        int idx = base + j; idx = idx < TDIM - 1 ? idx : TDIM - 1;
        f[j] = rowp[idx];
      }
    }
    // k-group 1 carries taps 8,9 then {1.0 (bias slot), 0,0,0,0,0}
    f[2] = g1 ? 1.0f : f[2];
    #pragma unroll
    for (int j = 3; j < 8; ++j) f[j] = g1 ? 0.0f : f[j];

    bf16x8 bfr;
    #pragma unroll
    for (int j = 0; j < 8; ++j) bfr[j] = f2bf(f[j]);

    f32x16 acc = {};
    acc = __builtin_amdgcn_mfma_f32_32x32x16_bf16(af, bfr, acc, 0, 0, 0);

    // ---- layer 2: relu-dot over this lane's 16 channels (b1 already in acc) ----
    float p0 = 0.f, p1 = 0.f;
    #pragma unroll
    for (int r = 0; r < 16; r += 2) {
      p0 = fmaf(fmaxf(acc[r],     0.f), w2v[r],     p0);
      p1 = fmaf(fmaxf(acc[r + 1], 0.f), w2v[r + 1], p1);
    }
    float p = p0 + p1;
    p += __shfl_xor(p, 32, 64);                // combine channel halves (lane L ^ L+32)
    const float z = p + b2c;
    const float y = 0.5f / (1.f + __expf(-z));

    const int t = t0 + n;
    if (lid < 32 && t < TVALID) {
      orow[WINDOW + t] = y;
      if (t == 0) {                            // 10-wide head broadcast of h[:,0]
        #pragma unroll
        for (int j = 0; j < WINDOW; ++j) orow[j] = y;
      }
    }
  }
}

extern "C" void kernel_launch(void* const* d_in, const int* in_sizes, int n_in,
                              void* d_out, int out_size, void* d_ws, size_t ws_size,
                              hipStream_t stream) {
  const float* ret = (const float*)d_in[0];
  const float* W1  = (const float*)d_in[1];
  const float* b1  = (const float*)d_in[2];
  const float* W2  = (const float*)d_in[3];
  const float* b2  = (const float*)d_in[4];
  float* out = (float*)d_out;

  const int B = in_sizes[0] / TDIM;            // 2048
  dim3 block(256);                             // 4 waves: one per 1024-wide t-segment
  dim3 grid(B);                                // one block per batch row
  hipLaunchKernelGGL(hurst_mfma, grid, block, 0, stream,
                     ret, W1, b1, W2, b2, out);
}

// Round 3
// 47.465 us; speedup vs baseline: 1.9110x; 1.1924x over previous
//
#include <hip/hip_runtime.h>

#define WINDOW 10
#define TDIM 4096
#define TVALID (TDIM - WINDOW)   // 4086 valid outputs per row

typedef __attribute__((ext_vector_type(8))) short bf16x8;
typedef __attribute__((ext_vector_type(16))) float f32x16;

static __device__ __forceinline__ short f2bf(float f) {
  return (short)__builtin_bit_cast(unsigned short, (__bf16)f);   // RNE cvt
}

static __device__ __forceinline__ float half_sigmoid(float z) {
  // 0.5 * sigmoid(z); v_rcp_f32 (~1 ulp) instead of IEEE div sequence
  float e = __expf(-z);
#if __has_builtin(__builtin_amdgcn_rcpf)
  return 0.5f * __builtin_amdgcn_rcpf(1.0f + e);
#else
  return 0.5f / (1.0f + e);
#endif
}

__global__ __launch_bounds__(256) void hurst_mfma2(
    const float* __restrict__ ret, const float* __restrict__ W1,
    const float* __restrict__ b1,  const float* __restrict__ W2,
    const float* __restrict__ b2,  float* __restrict__ out) {
  const int lid = threadIdx.x & 63;
  const int wv  = threadIdx.x >> 6;     // wave = 1024-wide t-segment
  const int n   = lid & 31;
  const int g   = lid >> 5;
  const bool g1 = (g == 1);

  // ---- A fragment: W1 rows, b1 fused at k-slot 10; k=11..15 zero ----
  bf16x8 af;
  if (!g1) {
    #pragma unroll
    for (int j = 0; j < 8; ++j) af[j] = f2bf(W1[n * WINDOW + j]);
  } else {
    af[0] = f2bf(W1[n * WINDOW + 8]);
    af[1] = f2bf(W1[n * WINDOW + 9]);
    af[2] = f2bf(b1[n]);                // bias slot (B supplies 1.0 at k=10)
    #pragma unroll
    for (int j = 3; j < 8; ++j) af[j] = 0;   // -> B k=11..15 are don't-cares
  }

  // layer-2 weight per acc reg: D row m = (r&3)+8*(r>>2)+4*g  (HW-verified map)
  float w2v[16];
  #pragma unroll
  for (int r = 0; r < 16; ++r) w2v[r] = W2[(r & 3) + 8 * (r >> 2) + 4 * g];
  const float b2c = b2[0];

  const int row = blockIdx.x;
  const float* __restrict__ rowp = ret + (size_t)row * TDIM;
  float* __restrict__ orow = out + (size_t)row * TDIM;
  const int lbase = n + 8 * g;          // lane's k-base offset within a tile

  #pragma unroll 1
  for (int i = 0; i < 16; ++i) {        // 16 pairs of 32-wide tiles = 1024 t's
    const int t0 = wv * 1024 + i * 64;  // tile0 base (always load-safe)
    const int t1 = t0 + 32;             // tile1 base (clamp only at t1==4064)

    float f0[8], f1[8];
    #pragma unroll
    for (int j = 0; j < 8; ++j) f0[j] = rowp[t0 + lbase + j];
    if (t1 <= TDIM - 64) {              // uniform branch; only final pair clamps
      #pragma unroll
      for (int j = 0; j < 8; ++j) f1[j] = rowp[t1 + lbase + j];
    } else {
      #pragma unroll
      for (int j = 0; j < 8; ++j) {
        int idx = t1 + lbase + j; idx = idx < TDIM ? idx : TDIM - 1;
        f1[j] = rowp[idx];
      }
    }
    f0[2] = g1 ? 1.0f : f0[2];          // bias column; only needed fixup
    f1[2] = g1 ? 1.0f : f1[2];

    bf16x8 bv0, bv1;
    #pragma unroll
    for (int j = 0; j < 8; ++j) { bv0[j] = f2bf(f0[j]); bv1[j] = f2bf(f1[j]); }

    f32x16 acc0 = {}, acc1 = {};
    acc0 = __builtin_amdgcn_mfma_f32_32x32x16_bf16(af, bv0, acc0, 0, 0, 0);
    acc1 = __builtin_amdgcn_mfma_f32_32x32x16_bf16(af, bv1, acc1, 0, 0, 0);

    // layer-2 relu-dot, dual chains per tile for ILP
    float a0 = 0.f, a1 = 0.f, c0 = 0.f, c1 = 0.f;
    #pragma unroll
    for (int r = 0; r < 16; r += 2) {
      a0 = fmaf(fmaxf(acc0[r],     0.f), w2v[r],     a0);
      a1 = fmaf(fmaxf(acc0[r + 1], 0.f), w2v[r + 1], a1);
      c0 = fmaf(fmaxf(acc1[r],     0.f), w2v[r],     c0);
      c1 = fmaf(fmaxf(acc1[r + 1], 0.f), w2v[r + 1], c1);
    }
    float P0 = a0 + a1; P0 += __shfl_xor(P0, 32, 64);  // valid in all 64 lanes
    float P1 = c0 + c1; P1 += __shfl_xor(P1, 32, 64);

    // one sigmoid + one coalesced store for 64 outputs
    const float q = (lid < 32) ? P0 : P1;
    const float y = half_sigmoid(q + b2c);
    const int t = t0 + lid;
    if (t0 + 63 < TVALID) {             // uniform: all 64 valid
      orow[WINDOW + t] = y;
    } else if (t < TVALID) {
      orow[WINDOW + t] = y;
    }
    if (wv == 0 && i == 0) {            // uniform, once per block: head bcast
      const float y0 = __shfl(y, 0, 64);
      if (lid < WINDOW) orow[lid] = y0;
    }
  }
}

extern "C" void kernel_launch(void* const* d_in, const int* in_sizes, int n_in,
                              void* d_out, int out_size, void* d_ws, size_t ws_size,
                              hipStream_t stream) {
  const float* ret = (const float*)d_in[0];
  const float* W1  = (const float*)d_in[1];
  const float* b1  = (const float*)d_in[2];
  const float* W2  = (const float*)d_in[3];
  const float* b2  = (const float*)d_in[4];
  float* out = (float*)d_out;

  const int B = in_sizes[0] / TDIM;     // 2048
  dim3 block(256);                      // 4 waves x 1024-wide segments
  dim3 grid(B);
  hipLaunchKernelGGL(hurst_mfma2, grid, block, 0, stream,
                     ret, W1, b1, W2, b2, out);
}

// Round 4
// 42.488 us; speedup vs baseline: 2.1348x; 1.1171x over previous
//
#include <hip/hip_runtime.h>

#define WINDOW 10
#define TDIM 4096
#define TVALID (TDIM - WINDOW)   // 4086 valid outputs per row

typedef __attribute__((ext_vector_type(8)))  short bf16x8;   // MFMA operand (4 VGPRs)
typedef __attribute__((ext_vector_type(8)))  __bf16 bfv8;
typedef __attribute__((ext_vector_type(8)))  float f32x8;
typedef __attribute__((ext_vector_type(16))) float f32x16;
typedef __attribute__((ext_vector_type(2)))  float f32x2;
typedef float f32x4u __attribute__((ext_vector_type(4), aligned(4)));  // unaligned-ok vec load

static __device__ __forceinline__ short f2bf(float f) {
  return (short)__builtin_bit_cast(unsigned short, (__bf16)f);
}

// 8 consecutive floats -> bf16x8 fragment, bias slot (k=10 -> elem 2) forced to 1.0 on g1
static __device__ __forceinline__ bf16x8 cvt8(const float* __restrict__ p, bool g1) {
  f32x4u a = *(const f32x4u*)p;
  f32x4u b = *(const f32x4u*)(p + 4);
  f32x8 f;
  f[0] = a[0]; f[1] = a[1]; f[2] = g1 ? 1.0f : a[2]; f[3] = a[3];
  f[4] = b[0]; f[5] = b[1]; f[6] = b[2]; f[7] = b[3];
  return __builtin_bit_cast(bf16x8, __builtin_convertvector(f, bfv8));  // v_cvt_pk_bf16_f32 x4
}

static __device__ __forceinline__ bf16x8 cvt8_clamp(const float* __restrict__ rowp,
                                                    int base, bool g1) {
  f32x8 f;
  #pragma unroll
  for (int j = 0; j < 8; ++j) {
    int idx = base + j; idx = idx < TDIM - 1 ? idx : TDIM - 1;
    f[j] = rowp[idx];
  }
  f[2] = g1 ? 1.0f : f[2];
  return __builtin_bit_cast(bf16x8, __builtin_convertvector(f, bfv8));
}

// layer-2 relu-dot over this lane's 16 channels, packed fp32 (v_pk_max/v_pk_fma)
static __device__ __forceinline__ float l2dot(const f32x16& acc, const f32x2* __restrict__ w2p) {
  const f32x2 z2 = {0.f, 0.f};
  f32x2 s0 = z2, s1 = z2;
  #pragma unroll
  for (int j = 0; j < 8; j += 2) {
    f32x2 a = {acc[2*j],     acc[2*j + 1]};
    f32x2 b = {acc[2*j + 2], acc[2*j + 3]};
    s0 = __builtin_elementwise_fma(__builtin_elementwise_max(a, z2), w2p[j],     s0);
    s1 = __builtin_elementwise_fma(__builtin_elementwise_max(b, z2), w2p[j + 1], s1);
  }
  f32x2 s = s0 + s1;
  return s[0] + s[1];
}

static __device__ __forceinline__ float half_sigmoid(float z) {
  float e = __expf(-z);
  return 0.5f * __frcp_rn(1.0f + e) ;
}

__global__ __launch_bounds__(256) void hurst_mfma3(
    const float* __restrict__ ret, const float* __restrict__ W1,
    const float* __restrict__ b1,  const float* __restrict__ W2,
    const float* __restrict__ b2,  float* __restrict__ out) {
  const int lid = threadIdx.x & 63;
  const int wv  = threadIdx.x >> 6;      // wave = 1024-wide t-segment
  const int n   = lid & 31;
  const int g   = lid >> 5;
  const bool g1 = (g == 1);

  // A fragment: W1 rows, b1 fused at k-slot 10 (B supplies 1.0 there); k=11..15 zero
  bf16x8 af;
  if (!g1) {
    #pragma unroll
    for (int j = 0; j < 8; ++j) af[j] = f2bf(W1[n * WINDOW + j]);
  } else {
    af[0] = f2bf(W1[n * WINDOW + 8]);
    af[1] = f2bf(W1[n * WINDOW + 9]);
    af[2] = f2bf(b1[n]);
    #pragma unroll
    for (int j = 3; j < 8; ++j) af[j] = 0;   // B k=11..15 are don't-cares
  }

  // layer-2 weights per acc reg pair: D row m = (r&3)+8*(r>>2)+4*g (HW-verified map)
  f32x2 w2p[8];
  #pragma unroll
  for (int j = 0; j < 8; ++j) {
    w2p[j][0] = W2[((2*j)   & 3) + 8 * ((2*j)   >> 2) + 4 * g];
    w2p[j][1] = W2[((2*j+1) & 3) + 8 * ((2*j+1) >> 2) + 4 * g];
  }
  const float b2c = b2[0];

  const int row = blockIdx.x;
  const float* __restrict__ rowp = ret + (size_t)row * TDIM;
  float* __restrict__ orow = out + (size_t)row * TDIM;
  const int seg   = wv * 1024;
  const int lbase = n + 8 * g;           // lane's element offset within a tile
  const float* __restrict__ lanep = rowp + seg + lbase;

  float y;

  // ---- tile-pair body: 64 outputs, one sigmoid + one coalesced store ----
#define BODY(I, CLAMPED, PRED)                                               \
  {                                                                          \
    const int t0 = seg + (I) * 64;                                           \
    bf16x8 bv0 = cvt8(lanep + (I) * 64, g1);                                 \
    bf16x8 bv1 = (CLAMPED) ? cvt8_clamp(rowp, t0 + 32 + lbase, g1)           \
                           : cvt8(lanep + (I) * 64 + 32, g1);                \
    f32x16 acc0 = {}, acc1 = {};                                             \
    acc0 = __builtin_amdgcn_mfma_f32_32x32x16_bf16(af, bv0, acc0, 0, 0, 0);  \
    acc1 = __builtin_amdgcn_mfma_f32_32x32x16_bf16(af, bv1, acc1, 0, 0, 0);  \
    float P0 = l2dot(acc0, w2p);                                             \
    float P1 = l2dot(acc1, w2p);                                             \
    P0 += __shfl_xor(P0, 32, 64);                                            \
    P1 += __shfl_xor(P1, 32, 64);                                            \
    const float q = (lid < 32) ? P0 : P1;                                    \
    y = half_sigmoid(q + b2c);                                               \
    const int t = t0 + lid;                                                  \
    if (!(PRED) || t < TVALID) orow[WINDOW + t] = y;                         \
  }

  BODY(0, false, false)                   // peeled: head broadcast lives here
  if (wv == 0) {
    const float y0 = __shfl(y, 0, 64);
    if (lid < WINDOW) orow[lid] = y0;
  }

  #pragma unroll
  for (int i = 1; i < 15; ++i) BODY(i, false, false)   // branch-free, imm offsets

  if (wv < 3) {
    BODY(15, false, false)
  } else {
    BODY(15, true, true)                  // t0=4032: clamp tile1 loads, mask stores
  }
#undef BODY
}

extern "C" void kernel_launch(void* const* d_in, const int* in_sizes, int n_in,
                              void* d_out, int out_size, void* d_ws, size_t ws_size,
                              hipStream_t stream) {
  const float* ret = (const float*)d_in[0];
  const float* W1  = (const float*)d_in[1];
  const float* b1  = (const float*)d_in[2];
  const float* W2  = (const float*)d_in[3];
  const float* b2  = (const float*)d_in[4];
  float* out = (float*)d_out;

  const int B = in_sizes[0] / TDIM;      // 2048
  dim3 block(256);                       // 4 waves x 1024-wide segments
  dim3 grid(B);
  hipLaunchKernelGGL(hurst_mfma3, grid, block, 0, stream,
                     ret, W1, b1, W2, b2, out);
}